// Round 6
// baseline (282.973 us; speedup 1.0000x reference)
//
#include <hip/hip_runtime.h>
#include <math.h>

#define Lq 2048
#define LDP2 40   // attn Pp row stride (ushorts)
#define PLANE ((size_t)8192 * 512)

typedef __attribute__((ext_vector_type(8))) __bf16 bf16x8;
typedef __attribute__((ext_vector_type(4))) float f32x4;
#define MFMA16(a,b,c) __builtin_amdgcn_mfma_f32_16x16x32_bf16(a,b,c,0,0,0)

#if __has_builtin(__builtin_amdgcn_exp2f)
#define EXP2F(x) __builtin_amdgcn_exp2f(x)
#else
#define EXP2F(x) exp2f(x)
#endif

__device__ __forceinline__ void async16(const void* g, void* l) {
    __builtin_amdgcn_global_load_lds(
        (const __attribute__((address_space(1))) unsigned int*)g,
        (__attribute__((address_space(3))) unsigned int*)l, 16, 0, 0);
}

// truncation split: x = hi + lo (+ ~2^-16 rel residual)
__device__ __forceinline__ void splitbf(float x, ushort& h, ushort& l) {
    unsigned u = __float_as_uint(x);
    h = (ushort)(u >> 16);
    float hf = __uint_as_float(u & 0xffff0000u);
    l = (ushort)(__float_as_uint(x - hf) >> 16);
}
// round-to-nearest-even bf16
__device__ __forceinline__ ushort rnebf(float x) {
    unsigned u = __float_as_uint(x);
    return (ushort)((u + 0x7fffu + ((u >> 16) & 1u)) >> 16);
}

// ---- activation fp32 [8192][512] -> hi/lo bf16 planes ----
__global__ __launch_bounds__(256) void asplit_kernel(
    const float* __restrict__ A, ushort* __restrict__ Ah, ushort* __restrict__ Al)
{
    size_t i = ((size_t)blockIdx.x * 256 + threadIdx.x) * 4;
    float4 v = *(const float4*)(A + i);
    ushort4 h, l;
    splitbf(v.x, h.x, l.x); splitbf(v.y, h.y, l.y);
    splitbf(v.z, h.z, l.z); splitbf(v.w, h.w, l.w);
    *(ushort4*)(Ah + i) = h;
    *(ushort4*)(Al + i) = l;
}

// ---- W [512k][512n] fp32 -> WT [z*512 + n][k] bf16 hi/lo planes, z in [0,4) ----
__global__ __launch_bounds__(256) void wsplit4_kernel(
    const float* __restrict__ W0, const float* __restrict__ W1,
    const float* __restrict__ W2, const float* __restrict__ W3,
    ushort* __restrict__ WTh, ushort* __restrict__ WTl)
{
    __shared__ float T[64][65];
    const int z = blockIdx.z;
    const float* W = (z == 0) ? W0 : (z == 1) ? W1 : (z == 2) ? W2 : W3;
    const int k0 = blockIdx.x * 64, n0 = blockIdx.y * 64;
    const int tid = threadIdx.x;
    #pragma unroll
    for (int i = 0; i < 4; ++i) {
        int u = tid + i * 256;
        int row = u >> 4, c4 = (u & 15) * 4;
        float4 v = *(const float4*)(W + (size_t)(k0 + row) * 512 + n0 + c4);
        T[row][c4 + 0] = v.x; T[row][c4 + 1] = v.y; T[row][c4 + 2] = v.z; T[row][c4 + 3] = v.w;
    }
    __syncthreads();
    #pragma unroll
    for (int i = 0; i < 2; ++i) {
        int u = tid + i * 256;
        int d = u >> 3, c8 = (u & 7) * 8;
        ushort hs[8], ls[8];
        #pragma unroll
        for (int j = 0; j < 8; ++j) splitbf(T[c8 + j][d], hs[j], ls[j]);
        uint4 wh, wl;
        wh.x = hs[0] | ((unsigned)hs[1] << 16); wh.y = hs[2] | ((unsigned)hs[3] << 16);
        wh.z = hs[4] | ((unsigned)hs[5] << 16); wh.w = hs[6] | ((unsigned)hs[7] << 16);
        wl.x = ls[0] | ((unsigned)ls[1] << 16); wl.y = ls[2] | ((unsigned)ls[3] << 16);
        wl.z = ls[4] | ((unsigned)ls[5] << 16); wl.w = ls[6] | ((unsigned)ls[7] << 16);
        size_t off = (size_t)(z * 512 + n0 + d) * 512 + k0 + c8;
        *(uint4*)(WTh + off) = wh;
        *(uint4*)(WTl + off) = wl;
    }
}

// ---- GEMM3: 128x64 tile, BK=32, all-async dbuf staging, 48KB LDS (3 blocks/CU) ----
// mode 0: Q split planes (O1,O2); 1: K hi plane (O1); 2: V^T split planes (O1,O2); 3: fp32 Cf
union G3 {
    struct { ushort A[2][2][4096]; ushort B[2][2][2048]; } s;
    ushort E[24576];
};

__global__ __launch_bounds__(256) void gemm3_kernel(
    const ushort* __restrict__ Ah, const ushort* __restrict__ Al,
    const ushort* __restrict__ BhT, const ushort* __restrict__ BlT,
    const float* __restrict__ bias, int nbase, int mode,
    float* __restrict__ Cf, ushort* __restrict__ O1, ushort* __restrict__ O2)
{
    __shared__ __align__(16) G3 g3;
    const int tid = threadIdx.x;
    const int wave = tid >> 6, lane = tid & 63;
    const int l15 = lane & 15, quad = lane >> 4;
    const int m0 = blockIdx.x * 128;
    const int n0 = blockIdx.y * 64;
    const int nglob = nbase + n0;
    const int wm = (wave & 1) * 64, wn = (wave >> 1) * 32;
    const int swz8 = (quad ^ ((l15 >> 1) & 3)) * 8;

    // staging: slot s -> row = s>>2, stored col-group g' = s&3, src col-group g = g' ^ ((row>>1)&3)
    const int sA1 = tid + 256;
    const int rA0 = tid >> 2, gA0 = (tid & 3) ^ ((rA0 >> 1) & 3);
    const int rA1 = sA1 >> 2, gA1 = (sA1 & 3) ^ ((rA1 >> 1) & 3);
    const int rB = tid >> 2, gB = (tid & 3) ^ ((rB >> 1) & 3);
    const ushort* pAh0 = Ah + (size_t)(m0 + rA0) * 512 + gA0 * 8;
    const ushort* pAh1 = Ah + (size_t)(m0 + rA1) * 512 + gA1 * 8;
    const ushort* pAl0 = Al + (size_t)(m0 + rA0) * 512 + gA0 * 8;
    const ushort* pAl1 = Al + (size_t)(m0 + rA1) * 512 + gA1 * 8;
    const ushort* pBh = BhT + (size_t)(nglob + rB) * 512 + gB * 8;
    const ushort* pBl = BlT + (size_t)(nglob + rB) * 512 + gB * 8;

    f32x4 acc[4][2];
    #pragma unroll
    for (int i = 0; i < 4; ++i)
        #pragma unroll
        for (int j = 0; j < 2; ++j) acc[i][j] = (f32x4){0.f, 0.f, 0.f, 0.f};

    // prologue: stage tile 0 into buf 0
    async16(pAh0, &g3.s.A[0][0][tid * 8]);
    async16(pAh1, &g3.s.A[0][0][sA1 * 8]);
    async16(pAl0, &g3.s.A[0][1][tid * 8]);
    async16(pAl1, &g3.s.A[0][1][sA1 * 8]);
    async16(pBh,  &g3.s.B[0][0][tid * 8]);
    async16(pBl,  &g3.s.B[0][1][tid * 8]);

    for (int t = 0; t < 16; ++t) {
        const int p = t & 1;
        __syncthreads();   // drains DMA(t); reads of buf 1-p finished
        if (t < 15) {
            const int kk = (t + 1) * 32;
            async16(pAh0 + kk, &g3.s.A[1 - p][0][tid * 8]);
            async16(pAh1 + kk, &g3.s.A[1 - p][0][sA1 * 8]);
            async16(pAl0 + kk, &g3.s.A[1 - p][1][tid * 8]);
            async16(pAl1 + kk, &g3.s.A[1 - p][1][sA1 * 8]);
            async16(pBh + kk,  &g3.s.B[1 - p][0][tid * 8]);
            async16(pBl + kk,  &g3.s.B[1 - p][1][tid * 8]);
        }
        bf16x8 afh[4], afl[4];
        #pragma unroll
        for (int ms = 0; ms < 4; ++ms) {
            int off = (wm + ms * 16 + l15) * 32 + swz8;
            afh[ms] = *(const bf16x8*)&g3.s.A[p][0][off];
            afl[ms] = *(const bf16x8*)&g3.s.A[p][1][off];
        }
        #pragma unroll
        for (int ns = 0; ns < 2; ++ns) {
            int off = (wn + ns * 16 + l15) * 32 + swz8;
            bf16x8 bfh = *(const bf16x8*)&g3.s.B[p][0][off];
            bf16x8 bfl = *(const bf16x8*)&g3.s.B[p][1][off];
            #pragma unroll
            for (int ms = 0; ms < 4; ++ms) {
                acc[ms][ns] = MFMA16(afh[ms], bfl, acc[ms][ns]);
                acc[ms][ns] = MFMA16(afl[ms], bfh, acc[ms][ns]);
                acc[ms][ns] = MFMA16(afh[ms], bfh, acc[ms][ns]);
            }
        }
    }

    // bias
    #pragma unroll
    for (int ns = 0; ns < 2; ++ns) {
        float bv = bias[n0 + wn + ns * 16 + l15];
        #pragma unroll
        for (int ms = 0; ms < 4; ++ms)
            #pragma unroll
            for (int r = 0; r < 4; ++r) acc[ms][ns][r] += bv;
    }

    if (mode == 3) {   // coalesced fp32 stores
        #pragma unroll
        for (int ns = 0; ns < 2; ++ns) {
            int col = n0 + wn + ns * 16 + l15;
            #pragma unroll
            for (int ms = 0; ms < 4; ++ms)
                #pragma unroll
                for (int r = 0; r < 4; ++r)
                    Cf[(size_t)(m0 + wm + ms * 16 + quad * 4 + r) * 512 + col] = acc[ms][ns][r];
        }
        return;
    }

    const int h0 = n0 >> 6;
    const int b = m0 >> 11, rr0 = m0 & 2047;
    const int passes = (mode == 1) ? 1 : 2;
    for (int pass = 0; pass < passes; ++pass) {
        __syncthreads();
        #pragma unroll
        for (int ms = 0; ms < 4; ++ms) {
            #pragma unroll
            for (int ns = 0; ns < 2; ++ns) {
                int cl = wn + ns * 16 + l15;
                int rl = wm + ms * 16 + quad * 4;
                if (mode == 2) {
                    ushort4 w4;
                    #pragma unroll
                    for (int r = 0; r < 4; ++r) {
                        ushort h, l; splitbf(acc[ms][ns][r], h, l);
                        ((ushort*)&w4)[r] = pass ? l : h;
                    }
                    *(ushort4*)&g3.E[cl * 136 + rl] = w4;
                } else {
                    #pragma unroll
                    for (int r = 0; r < 4; ++r) {
                        float v = acc[ms][ns][r];
                        ushort out;
                        if (mode == 1) out = rnebf(v);
                        else { ushort h, l; splitbf(v, h, l); out = pass ? l : h; }
                        g3.E[(rl + r) * 72 + cl] = out;
                    }
                }
            }
        }
        __syncthreads();
        if (mode == 2) {
            ushort* dst = pass ? O2 : O1;
            #pragma unroll
            for (int i = 0; i < 4; ++i) {
                int idx = tid + i * 256;
                int d = idx >> 4, rg = idx & 15;
                uint4 u = *(const uint4*)&g3.E[d * 136 + rg * 8];
                *(uint4*)&dst[((size_t)(b * 8 + h0) * 64 + d) * 2048 + rr0 + rg * 8] = u;
            }
        } else {
            ushort* dst = (mode == 0) ? (pass ? O2 : O1) : O1;
            #pragma unroll
            for (int i = 0; i < 4; ++i) {
                int idx = tid + i * 256;
                int row = idx >> 3, cg = idx & 7;
                uint4 u = *(const uint4*)&g3.E[row * 72 + cg * 8];
                *(uint4*)&dst[((size_t)(b * 8 + h0) * 2048 + rr0 + row) * 64 + cg * 8] = u;
            }
        }
    }
}

// ---- Flash attention, S^T dataflow, in-block split-K, async dbuf, 512 threads ----
union SmemU {
    struct { ushort KVs[2][6][4096]; ushort Pp[8][64 * LDP2]; } p1;
    struct { float Obuf[4][64 * 68]; float Lbuf[4][64]; } p2;
};

__global__ __launch_bounds__(512, 2) void attn3_kernel(
    const ushort* __restrict__ Qh, const ushort* __restrict__ Ql,
    const ushort* __restrict__ Kh, const ushort* __restrict__ VhT,
    const ushort* __restrict__ VlT, const int* __restrict__ mask,
    ushort* __restrict__ XSh, ushort* __restrict__ XSl)
{
    __shared__ SmemU smem;
    const int tid = threadIdx.x;
    const int wave = tid >> 6, lane = tid & 63;
    const int l15 = lane & 15, quad = lane >> 4;
    const int w4 = wave & 3, half = wave >> 2;
    const int bh = blockIdx.x, b = bh >> 3, h = bh & 7;
    const int q0 = blockIdx.y * 256;

    bf16x8 qh[4][2], ql[4][2];
    #pragma unroll
    for (int qs = 0; qs < 4; ++qs) {
        size_t qb = ((size_t)bh * 2048 + q0 + w4 * 64 + qs * 16 + l15) * 64 + quad * 8;
        qh[qs][0] = *(const bf16x8*)(Qh + qb);
        qh[qs][1] = *(const bf16x8*)(Qh + qb + 32);
        ql[qs][0] = *(const bf16x8*)(Ql + qb);
        ql[qs][1] = *(const bf16x8*)(Ql + qb + 32);
    }

    const f32x4 z = {0.f, 0.f, 0.f, 0.f};
    f32x4 oacc[4][4];
    #pragma unroll
    for (int i = 0; i < 4; ++i)
        #pragma unroll
        for (int j = 0; j < 4; ++j) oacc[i][j] = z;
    float lacc[4] = {0.f, 0.f, 0.f, 0.f};

    const int rloc = lane >> 3, gs = (lane & 7) ^ rloc;
    const ushort* sb[6]; size_t sstep[6]; int dofs[6];
    #pragma unroll
    for (int i = 0; i < 6; ++i) {
        int cc = wave * 6 + i;
        int hc = cc / 24, r24 = cc % 24, pc = r24 >> 3, ic = r24 & 7;
        if (pc == 0) {
            sb[i] = Kh + ((size_t)(bh * 2048 + hc * 1024 + ic * 8 + rloc)) * 64 + gs * 8;
            sstep[i] = (size_t)64 * 64;
        } else {
            const ushort* vp = (pc == 1) ? VhT : VlT;
            sb[i] = vp + ((size_t)(bh * 64 + ic * 8 + rloc)) * 2048 + hc * 1024 + gs * 8;
            sstep[i] = 64;
        }
        dofs[i] = (hc * 3 + pc) * 4096 + ic * 512;
    }

    const int sw0 = (quad ^ (l15 & 7)) * 8;
    const int mrow0 = b * 2048 + half * 1024;
    const float C8 = 0.18033688011112043f;   // log2(e)/8

    #pragma unroll
    for (int i = 0; i < 6; ++i)
        async16(sb[i], &smem.p1.KVs[0][0][0] + dofs[i]);

    for (int t = 0; t < 16; ++t) {
        __syncthreads();
        if (t < 15) {
            #pragma unroll
            for (int i = 0; i < 6; ++i)
                async16(sb[i] + (size_t)(t + 1) * sstep[i], &smem.p1.KVs[(t + 1) & 1][0][0] + dofs[i]);
        }
        const int p = t & 1;
        const ushort* K0 = smem.p1.KVs[p][half * 3 + 0];
        const ushort* V0 = smem.p1.KVs[p][half * 3 + 1];
        const ushort* V1 = smem.p1.KVs[p][half * 3 + 2];
        ushort* Pw = smem.p1.Pp[wave];

        #pragma unroll
        for (int ks = 0; ks < 2; ++ks) {
            #pragma unroll
            for (int kt2 = 0; kt2 < 2; ++kt2) {
                const int kt = ks * 2 + kt2;
                const int kb = (kt * 16 + l15) * 64;
                bf16x8 ka0 = *(const bf16x8*)&K0[kb + sw0];
                bf16x8 ka1 = *(const bf16x8*)&K0[kb + (sw0 ^ 32)];
                int4 mv = *(const int4*)(mask + mrow0 + t * 64 + kt * 16 + quad * 4);
                float bias[4];
                bias[0] = mv.x ? 0.f : -1e38f; bias[1] = mv.y ? 0.f : -1e38f;
                bias[2] = mv.z ? 0.f : -1e38f; bias[3] = mv.w ? 0.f : -1e38f;
                #pragma unroll
                for (int qs = 0; qs < 4; ++qs) {
                    f32x4 a = z;
                    a = MFMA16(ka0, ql[qs][0], a);
                    a = MFMA16(ka1, ql[qs][1], a);
                    a = MFMA16(ka0, qh[qs][0], a);
                    a = MFMA16(ka1, qh[qs][1], a);
                    ushort4 hv;
                    #pragma unroll
                    for (int r = 0; r < 4; ++r) {
                        float pv = EXP2F(fmaf(a[r], C8, bias[r]));
                        unsigned u = __float_as_uint(pv);
                        unsigned hu = (u + 0x7fffu + ((u >> 16) & 1u)) & 0xffff0000u;
                        lacc[qs] += __uint_as_float(hu);
                        ((ushort*)&hv)[r] = (ushort)(hu >> 16);
                    }
                    *(ushort4*)&Pw[(qs * 16 + l15) * LDP2 + kt2 * 16 + quad * 4] = hv;
                }
            }
            const int svo = sw0 ^ (ks * 32);
            bf16x8 pf[4];
            #pragma unroll
            for (int qs = 0; qs < 4; ++qs)
                pf[qs] = *(const bf16x8*)&Pw[(qs * 16 + l15) * LDP2 + quad * 8];
            #pragma unroll
            for (int dsub = 0; dsub < 4; ++dsub) {
                const int vb = (dsub * 16 + l15) * 64;
                bf16x8 vh = *(const bf16x8*)&V0[vb + svo];
                bf16x8 vl = *(const bf16x8*)&V1[vb + svo];
                #pragma unroll
                for (int qs = 0; qs < 4; ++qs) {
                    oacc[qs][dsub] = MFMA16(vl, pf[qs], oacc[qs][dsub]);
                    oacc[qs][dsub] = MFMA16(vh, pf[qs], oacc[qs][dsub]);
                }
            }
        }
    }

    float lv[4];
    #pragma unroll
    for (int qs = 0; qs < 4; ++qs) {
        float v = lacc[qs];
        v += __shfl_xor(v, 16);
        v += __shfl_xor(v, 32);
        lv[qs] = v;
    }

    __syncthreads();
    if (half == 1) {
        #pragma unroll
        for (int qs = 0; qs < 4; ++qs) {
            #pragma unroll
            for (int dsub = 0; dsub < 4; ++dsub) {
                float4 o4 = {oacc[qs][dsub][0], oacc[qs][dsub][1], oacc[qs][dsub][2], oacc[qs][dsub][3]};
                *(float4*)&smem.p2.Obuf[w4][(qs * 16 + l15) * 68 + dsub * 16 + quad * 4] = o4;
            }
            if (quad == 0) smem.p2.Lbuf[w4][qs * 16 + l15] = lv[qs];
        }
    }
    __syncthreads();
    if (half == 0) {
        #pragma unroll
        for (int qs = 0; qs < 4; ++qs) {
            float ltot = lv[qs] + smem.p2.Lbuf[w4][qs * 16 + l15];
            float inv = (ltot > 0.f) ? 1.f / ltot : 0.f;
            int row = q0 + w4 * 64 + qs * 16 + l15;
            size_t base = ((size_t)(b * 2048 + row)) * 512 + h * 64;
            #pragma unroll
            for (int dsub = 0; dsub < 4; ++dsub) {
                float4 p4 = *(const float4*)&smem.p2.Obuf[w4][(qs * 16 + l15) * 68 + dsub * 16 + quad * 4];
                float o0 = (oacc[qs][dsub][0] + p4.x) * inv;
                float o1 = (oacc[qs][dsub][1] + p4.y) * inv;
                float o2 = (oacc[qs][dsub][2] + p4.z) * inv;
                float o3 = (oacc[qs][dsub][3] + p4.w) * inv;
                ushort4 hv, lw;
                splitbf(o0, hv.x, lw.x); splitbf(o1, hv.y, lw.y);
                splitbf(o2, hv.z, lw.z); splitbf(o3, hv.w, lw.w);
                *(ushort4*)(XSh + base + dsub * 16 + quad * 4) = hv;
                *(ushort4*)(XSl + base + dsub * 16 + quad * 4) = lw;
            }
        }
    }
}

extern "C" void kernel_launch(void* const* d_in, const int* in_sizes, int n_in,
                              void* d_out, int out_size, void* d_ws, size_t ws_size,
                              hipStream_t stream) {
    const float* query = (const float*)d_in[0];
    const float* key   = (const float*)d_in[1];
    const float* value = (const float*)d_in[2];
    const int*   mask  = (const int*)d_in[3];
    const float* Wq = (const float*)d_in[4];
    const float* bq = (const float*)d_in[5];
    const float* Wk = (const float*)d_in[6];
    const float* bk = (const float*)d_in[7];
    const float* Wv = (const float*)d_in[8];
    const float* bv = (const float*)d_in[9];
    const float* Wo = (const float*)d_in[10];
    const float* bo = (const float*)d_in[11];

    char* w = (char*)d_ws;
    const size_t MB = (size_t)1 << 20;
    ushort* Qh  = (ushort*)(w + 0 * MB);
    ushort* Ql  = (ushort*)(w + 8 * MB);
    ushort* Khp = (ushort*)(w + 16 * MB);
    ushort* VhT = (ushort*)(w + 24 * MB);
    ushort* VlT = (ushort*)(w + 32 * MB);
    ushort* Aih = (ushort*)(w + 40 * MB);   // 8 MB, live asplit->gemm
    ushort* Ail = (ushort*)(w + 48 * MB);   // 8 MB
    ushort* XSh = (ushort*)(w + 40 * MB);   // overlays Ai (live only after QKV gemms)
    ushort* XSl = (ushort*)(w + 48 * MB);
    ushort* WTh = (ushort*)(w + 56 * MB);   // [2048][512] = 2 MB
    ushort* WTl = (ushort*)(w + 58 * MB);

    wsplit4_kernel<<<dim3(8, 8, 4), 256, 0, stream>>>(Wq, Wk, Wv, Wo, WTh, WTl);

    asplit_kernel<<<4096, 256, 0, stream>>>(query, Aih, Ail);
    gemm3_kernel<<<dim3(64, 8), 256, 0, stream>>>(
        Aih, Ail, WTh, WTl, bq, 0, 0, nullptr, Qh, Ql);
    asplit_kernel<<<4096, 256, 0, stream>>>(key, Aih, Ail);
    gemm3_kernel<<<dim3(64, 8), 256, 0, stream>>>(
        Aih, Ail, WTh, WTl, bk, 512, 1, nullptr, Khp, nullptr);
    asplit_kernel<<<4096, 256, 0, stream>>>(value, Aih, Ail);
    gemm3_kernel<<<dim3(64, 8), 256, 0, stream>>>(
        Aih, Ail, WTh, WTl, bv, 1024, 2, nullptr, VhT, VlT);

    attn3_kernel<<<dim3(32, 8), 512, 0, stream>>>(Qh, Ql, Khp, VhT, VlT, mask, XSh, XSl);

    gemm3_kernel<<<dim3(64, 8), 256, 0, stream>>>(
        XSh, XSl, WTh, WTl, bo, 1536, 3, (float*)d_out, nullptr, nullptr);
}